// Round 9
// baseline (887.683 us; speedup 1.0000x reference)
//
#include <hip/hip_runtime.h>

#define PROP_ALPHA 0.1f
#define PROP_KSTEPS 10
#define PROP_BLOCKS 2048

// ---------------- CSR build ----------------

__global__ void hist_kernel(const int* __restrict__ dst, int* __restrict__ degI, int E) {
    int e = blockIdx.x * blockDim.x + threadIdx.x;
    if (e < E) atomicAdd(&degI[dst[e]], 1);
}

__global__ void dinv_kernel(const int* __restrict__ degI, float* __restrict__ dinv, int N) {
    int i = blockIdx.x * blockDim.x + threadIdx.x;
    if (i < N) {
        float d = (float)(degI[i] + 1);   // + self loop
        dinv[i] = rsqrtf(d);
    }
}

// ---- 3-kernel device-wide exclusive scan ----

__global__ __launch_bounds__(256) void scan1_kernel(const int* __restrict__ degI,
                                                    int* __restrict__ rowptr,
                                                    int* __restrict__ blockSums, int N) {
    __shared__ int s[256];
    int t = threadIdx.x;
    int idx = blockIdx.x * 256 + t;
    s[t] = (idx < N) ? degI[idx] : 0;
    __syncthreads();
    for (int off = 1; off < 256; off <<= 1) {
        int x = (t >= off) ? s[t - off] : 0;
        __syncthreads();
        s[t] += x;
        __syncthreads();
    }
    if (idx < N) rowptr[idx + 1] = s[t];
    if (t == 255) blockSums[blockIdx.x] = s[255];
    if (blockIdx.x == 0 && t == 0) rowptr[0] = 0;
}

__global__ __launch_bounds__(256) void scan2_kernel(int* __restrict__ blockSums, int nB) {
    __shared__ int s[256];
    int t = threadIdx.x;
    s[t] = (t < nB) ? blockSums[t] : 0;
    __syncthreads();
    for (int off = 1; off < 256; off <<= 1) {
        int x = (t >= off) ? s[t - off] : 0;
        __syncthreads();
        s[t] += x;
        __syncthreads();
    }
    if (t < nB) blockSums[t] = (t == 0) ? 0 : s[t - 1];
}

__global__ void scan3_kernel(int* __restrict__ rowptr, const int* __restrict__ blockSums,
                             int N) {
    int idx = blockIdx.x * 256 + threadIdx.x;
    if (idx < N) rowptr[idx + 1] += blockSums[blockIdx.x];
}

// edata[p] = { src, bitcast(norm) }
__global__ void scatter_kernel(const int* __restrict__ src, const int* __restrict__ dst,
                               const int* __restrict__ rowptr, int* __restrict__ rowctr,
                               const float* __restrict__ dinv,
                               int2* __restrict__ edata, int E) {
    int e = blockIdx.x * blockDim.x + threadIdx.x;
    if (e < E) {
        int d = dst[e], s = src[e];
        int p = rowptr[d] + atomicAdd(&rowctr[d], 1);
        int2 ed;
        ed.x = s;
        ed.y = __float_as_int(dinv[s] * dinv[d]);
        edata[p] = ed;
    }
}

// ---------------- fused MLP: h2 = relu(zx@W3 + v*b3^T)@W4 + b4 ----------------
// W3/W4 read from global inside the k-loop (broadcast float4, L2-hot; no
// register hoisting -> no spills). zsT transposed [k][row]; ts row-major
// [32][132] so layer-1 float4 writes are phase-optimal (8 distinct bank-quad
// starts). LDS 26.3 KB -> 6 blocks/CU.

__global__ __launch_bounds__(256) void fusedmlp_kernel(const float* __restrict__ zx,
                                                       const float* __restrict__ v,
                                                       const float* __restrict__ W3,
                                                       const float* __restrict__ b3,
                                                       const float* __restrict__ W4,
                                                       const float* __restrict__ b4,
                                                       float* __restrict__ h2, int N) {
    __shared__ float zsT[64 * 36];    // [k][row], padded stride 36
    __shared__ float ts[32 * 132];    // [row][k], padded stride 132
    __shared__ float vs[32];
    int t = threadIdx.x;
    int r0 = blockIdx.x * 32;
    int rows = min(32, N - r0);

    for (int idx = t; idx < 32 * 64; idx += 256) {
        int r = idx >> 6, c = idx & 63;
        zsT[c * 36 + r] = (r < rows) ? zx[(size_t)(r0 + r) * 64 + c] : 0.0f;
    }
    if (t < 32) vs[t] = (t < rows) ? v[r0 + t] : 0.0f;
    __syncthreads();

    // ---- layer 1: ts = relu(z @ W3 + v*b3^T): 32 rows x 128 cols ----
    {
        int cq = t & 31, rq = t >> 5;       // 32 col-groups x 8 row-groups
        int cb = cq * 4, rb = rq * 4;
        float4 b3v = *reinterpret_cast<const float4*>(&b3[cb]);
        float a[4][4];
        #pragma unroll
        for (int ri = 0; ri < 4; ++ri) {
            float vv = vs[rb + ri];
            a[ri][0] = vv * b3v.x; a[ri][1] = vv * b3v.y;
            a[ri][2] = vv * b3v.z; a[ri][3] = vv * b3v.w;
        }
        #pragma unroll 4
        for (int k = 0; k < 64; ++k) {
            float4 zq = *reinterpret_cast<const float4*>(&zsT[k * 36 + rb]);
            float4 wq = *reinterpret_cast<const float4*>(&W3[k * 128 + cb]);
            a[0][0] += zq.x * wq.x; a[0][1] += zq.x * wq.y;
            a[0][2] += zq.x * wq.z; a[0][3] += zq.x * wq.w;
            a[1][0] += zq.y * wq.x; a[1][1] += zq.y * wq.y;
            a[1][2] += zq.y * wq.z; a[1][3] += zq.y * wq.w;
            a[2][0] += zq.z * wq.x; a[2][1] += zq.z * wq.y;
            a[2][2] += zq.z * wq.z; a[2][3] += zq.z * wq.w;
            a[3][0] += zq.w * wq.x; a[3][1] += zq.w * wq.y;
            a[3][2] += zq.w * wq.z; a[3][3] += zq.w * wq.w;
        }
        #pragma unroll
        for (int ri = 0; ri < 4; ++ri) {
            float4 o;
            o.x = fmaxf(a[ri][0], 0.0f); o.y = fmaxf(a[ri][1], 0.0f);
            o.z = fmaxf(a[ri][2], 0.0f); o.w = fmaxf(a[ri][3], 0.0f);
            *reinterpret_cast<float4*>(&ts[(rb + ri) * 132 + cb]) = o;
        }
    }
    __syncthreads();

    // ---- layer 2: h2 = t @ W4 + b4: 32 rows x 64 cols ----
    {
        int cg = t & 15, rg = t >> 4;       // 16 col-groups x 16 row-groups
        int cb = cg * 4, rb = rg * 2;
        float4 b4v = *reinterpret_cast<const float4*>(&b4[cb]);
        float a[2][4];
        #pragma unroll
        for (int ri = 0; ri < 2; ++ri) {
            a[ri][0] = b4v.x; a[ri][1] = b4v.y; a[ri][2] = b4v.z; a[ri][3] = b4v.w;
        }
        #pragma unroll 4
        for (int k = 0; k < 128; ++k) {
            float t0 = ts[rb * 132 + k];
            float t1 = ts[(rb + 1) * 132 + k];
            float4 wq = *reinterpret_cast<const float4*>(&W4[k * 64 + cb]);
            a[0][0] += t0 * wq.x; a[0][1] += t0 * wq.y;
            a[0][2] += t0 * wq.z; a[0][3] += t0 * wq.w;
            a[1][0] += t1 * wq.x; a[1][1] += t1 * wq.y;
            a[1][2] += t1 * wq.z; a[1][3] += t1 * wq.w;
        }
        #pragma unroll
        for (int ri = 0; ri < 2; ++ri) {
            int r = rb + ri;
            if (r < rows) {
                float4 o = {a[ri][0], a[ri][1], a[ri][2], a[ri][3]};
                *reinterpret_cast<float4*>(&h2[(size_t)(r0 + r) * 64 + cb]) = o;
            }
        }
    }
}

// ---------------- propagation ----------------
// Persistent grid-stride waves: PROP_BLOCKS blocks resident once, each wave
// owns a contiguous node chunk (sequential edata stream). Per node: lane =
// channel, 1 edge per gather instr (256 B row), unroll x8 + pair tail.
// WITHV: broadcast vin[src] loads (same addr all lanes), lane 0 writes vout.

template <bool WITHV>
__global__ __launch_bounds__(256) void prop64_kernel(const float* __restrict__ zin,
                                                     const float* __restrict__ h,
                                                     const int* __restrict__ rowptr,
                                                     const int2* __restrict__ edata,
                                                     const float* __restrict__ dinv,
                                                     float* __restrict__ zout,
                                                     const float* __restrict__ vin,
                                                     float* __restrict__ vout,
                                                     int N, int firstOnes) {
    int wave = threadIdx.x >> 6;
    int lane = threadIdx.x & 63;
    int wglob = blockIdx.x * 4 + wave;
    int totalW = PROP_BLOCKS * 4;
    int chunk = (N + totalW - 1) / totalW;
    int i0 = wglob * chunk;
    int i1 = min(N, i0 + chunk);
    for (int i = i0; i < i1; ++i) {
        i = __builtin_amdgcn_readfirstlane(i);   // wave-uniform -> scalar CSR loads
        int beg = rowptr[i], end = rowptr[i + 1];
        float di = dinv[i];
        size_t li = (size_t)i * 64 + lane;
        float acc0 = di * di * zin[li];
        float acc1 = 0.0f, acc2 = 0.0f, acc3 = 0.0f;
        float vacc = 0.0f;
        int e = beg;
        for (; e + 8 <= end; e += 8) {
            int2 d0 = edata[e],     d1 = edata[e + 1], d2 = edata[e + 2], d3 = edata[e + 3];
            int2 d4 = edata[e + 4], d5 = edata[e + 5], d6 = edata[e + 6], d7 = edata[e + 7];
            float n0 = __int_as_float(d0.y), n1 = __int_as_float(d1.y);
            float n2 = __int_as_float(d2.y), n3 = __int_as_float(d3.y);
            float n4 = __int_as_float(d4.y), n5 = __int_as_float(d5.y);
            float n6 = __int_as_float(d6.y), n7 = __int_as_float(d7.y);
            float v0 = zin[(size_t)d0.x * 64 + lane];
            float v1 = zin[(size_t)d1.x * 64 + lane];
            float v2 = zin[(size_t)d2.x * 64 + lane];
            float v3 = zin[(size_t)d3.x * 64 + lane];
            float v4 = zin[(size_t)d4.x * 64 + lane];
            float v5 = zin[(size_t)d5.x * 64 + lane];
            float v6 = zin[(size_t)d6.x * 64 + lane];
            float v7 = zin[(size_t)d7.x * 64 + lane];
            if (WITHV) {
                if (firstOnes) {
                    vacc += (n0 + n1 + n2 + n3) + (n4 + n5 + n6 + n7);
                } else {
                    vacc += n0 * vin[d0.x] + n1 * vin[d1.x] + n2 * vin[d2.x]
                          + n3 * vin[d3.x] + n4 * vin[d4.x] + n5 * vin[d5.x]
                          + n6 * vin[d6.x] + n7 * vin[d7.x];
                }
            }
            acc0 += n0 * v0; acc1 += n1 * v1; acc2 += n2 * v2; acc3 += n3 * v3;
            acc0 += n4 * v4; acc1 += n5 * v5; acc2 += n6 * v6; acc3 += n7 * v7;
        }
        for (; e + 2 <= end; e += 2) {
            int2 d0 = edata[e], d1 = edata[e + 1];
            float n0 = __int_as_float(d0.y), n1 = __int_as_float(d1.y);
            float v0 = zin[(size_t)d0.x * 64 + lane];
            float v1 = zin[(size_t)d1.x * 64 + lane];
            if (WITHV) {
                vacc += firstOnes ? (n0 + n1) : (n0 * vin[d0.x] + n1 * vin[d1.x]);
            }
            acc0 += n0 * v0; acc1 += n1 * v1;
        }
        if (e < end) {
            int2 d0 = edata[e];
            float n0 = __int_as_float(d0.y);
            acc0 += n0 * zin[(size_t)d0.x * 64 + lane];
            if (WITHV) vacc += firstOnes ? n0 : n0 * vin[d0.x];
        }
        float acc = (acc0 + acc1) + (acc2 + acc3);
        float hv = h[li];
        zout[li] = (1.0f - PROP_ALPHA) * acc + PROP_ALPHA * hv;
        if (WITHV) {
            if (lane == 0) {
                float selfv = firstOnes ? 1.0f : vin[i];
                vout[i] = (1.0f - PROP_ALPHA) * (vacc + di * di * selfv) + PROP_ALPHA;
            }
        }
    }
}

// ---------------- launch ----------------

extern "C" void kernel_launch(void* const* d_in, const int* in_sizes, int n_in,
                              void* d_out, int out_size, void* d_ws, size_t ws_size,
                              hipStream_t stream) {
    const float* x  = (const float*)d_in[0];
    const int*   ei = (const int*)d_in[1];
    const float* W3 = (const float*)d_in[2];
    const float* b3 = (const float*)d_in[3];
    const float* W4 = (const float*)d_in[4];
    const float* b4 = (const float*)d_in[5];
    float* out = (float*)d_out;

    int N = in_sizes[0] / 64;   // IN_CH = 64
    int E = in_sizes[1] / 2;
    const int* srcA = ei;
    const int* dstA = ei + E;

    char* ws = (char*)d_ws;
    size_t off = 0;
    auto alloc = [&](size_t bytes) -> void* {
        void* p = ws + off;
        off = (off + bytes + 255) & ~(size_t)255;
        return p;
    };

    int nScanB = (N + 255) / 256;

    int*   degI   = (int*)alloc((size_t)N * 4);
    int*   rowptr = (int*)alloc(((size_t)N + 1) * 4);
    int*   rowctr = (int*)alloc((size_t)N * 4);
    int*   bsums  = (int*)alloc((size_t)nScanB * 4);
    float* dinv   = (float*)alloc((size_t)N * 4);
    int2*  edata  = (int2*)alloc((size_t)E * 8);
    float* vA     = (float*)alloc((size_t)N * 4);
    float* vB     = (float*)alloc((size_t)N * 4);
    float* zA     = (float*)alloc((size_t)N * 64 * 4);
    float* zB     = (float*)alloc((size_t)N * 64 * 4);
    float* hbuf   = (float*)alloc((size_t)N * 64 * 4);

    hipMemsetAsync(degI, 0, (size_t)N * 4, stream);
    hipMemsetAsync(rowctr, 0, (size_t)N * 4, stream);

    // --- CSR build ---
    hist_kernel<<<(E + 255) / 256, 256, 0, stream>>>(dstA, degI, E);
    dinv_kernel<<<(N + 255) / 256, 256, 0, stream>>>(degI, dinv, N);
    scan1_kernel<<<nScanB, 256, 0, stream>>>(degI, rowptr, bsums, N);
    scan2_kernel<<<1, 256, 0, stream>>>(bsums, nScanB);
    scan3_kernel<<<nScanB, 256, 0, stream>>>(rowptr, bsums, N);
    scatter_kernel<<<(E + 255) / 256, 256, 0, stream>>>(srcA, dstA, rowptr, rowctr,
                                                        dinv, edata, E);

    // --- prop1: zx = M*x with fused v = M*ones (broadcast loads) ---
    for (int s = 0; s < PROP_KSTEPS; ++s) {
        const float* in = (s == 0) ? x : ((s & 1) ? zA : zB);
        float*       o  = (s & 1) ? zB : zA;
        const float* vi = (s & 1) ? vA : vB;   // step0: unused (firstOnes)
        float*       vo = (s & 1) ? vB : vA;
        if (s == 0) vi = vB;                   // any valid pointer
        prop64_kernel<true><<<PROP_BLOCKS, 256, 0, stream>>>(
            in, x, rowptr, edata, dinv, o, vi, vo, N, s == 0 ? 1 : 0);
    }
    // zx in zB, v in vB

    // --- h2 = relu(zx@W3 + v*b3^T)@W4 + b4 ---
    fusedmlp_kernel<<<(N + 31) / 32, 256, 0, stream>>>(zB, vB, W3, b3, W4, b4, hbuf, N);

    // --- prop2: out = M*h2 ---
    for (int s = 0; s < PROP_KSTEPS; ++s) {
        const float* in = (s == 0) ? hbuf : ((s & 1) ? zA : zB);
        float*       o  = (s == PROP_KSTEPS - 1) ? out : ((s & 1) ? zB : zA);
        prop64_kernel<false><<<PROP_BLOCKS, 256, 0, stream>>>(
            in, hbuf, rowptr, edata, dinv, o, nullptr, nullptr, N, 0);
    }
}